// Round 2
// baseline (495.345 us; speedup 1.0000x reference)
//
#include <hip/hip_runtime.h>
#include <hip/hip_bf16.h>

#define T_DIM 512
#define L_DIM 128

typedef _Float16 h2 __attribute__((ext_vector_type(2)));

#if defined(__has_builtin)
#if __has_builtin(__builtin_amdgcn_fdot2)
#define HAS_FDOT2 1
#endif
#endif

__device__ __forceinline__ float fdot2_acc(h2 a, h2 b, float c) {
#ifdef HAS_FDOT2
    return __builtin_amdgcn_fdot2(a, b, c, false);
#else
    return c + (float)a.x * (float)b.x + (float)a.y * (float)b.y;
#endif
}

__device__ __forceinline__ h2 pack_f16(float a, float b) {
    return __builtin_bit_cast(h2, __builtin_amdgcn_cvt_pkrtz(a, b));
}

// Block = 256 threads (4 waves) = one batch chain.
// Wave w owns j in [32w, 32w+32). Lane = (ihalf, jj): ihalf = lane>>5 picks
// i-range [64*ihalf, 64*ihalf+64); each lane keeps its E column-half (32
// f16x2 pairs along i) in VGPRs. Per step: p (f16 pairs, LDS broadcast) dot
// E-registers, xor-32 shuffle combines i-halves, then log/exp + repack.
__global__ __launch_bounds__(256, 2) void crf_fwd_kernel(
    const float* __restrict__ feats,
    const float* __restrict__ transfer,
    const int* __restrict__ target,
    const int* __restrict__ startp,
    const int* __restrict__ stopp,
    float* __restrict__ out)
{
    __shared__ float LdsV[L_DIM];
    __shared__ unsigned int LdsP[L_DIM / 2] __attribute__((aligned(16)));
    __shared__ float LdsRed[16];

    const int tid   = threadIdx.x;
    const int lane  = tid & 63;
    const int wv    = tid >> 6;
    const int jj    = lane & 31;
    const int ihalf = lane >> 5;            // 0 or 1
    const int j     = (wv << 5) | jj;       // 0..127, dup across ihalf
    const int i0    = ihalf << 6;           // 0 or 64
    const int b     = blockIdx.x;
    const int start = startp[0];
    const int stop  = stopp[0];
    const float* fbase = feats + (size_t)b * T_DIM * L_DIM;

    // ---- one-time: E column-half into registers (f16 pairs along i) ----
    h2 Ecol[32];
#pragma unroll
    for (int q = 0; q < 32; ++q) {
        float e0 = __expf(transfer[(i0 + 2 * q)     * L_DIM + j]);
        float e1 = __expf(transfer[(i0 + 2 * q + 1) * L_DIM + j]);
        Ecol[q] = pack_f16(e0, e1);
    }
    const float trStop = transfer[j * L_DIM + stop];

    // prep(v): share v across waves, global max m, p = exp(v-m) packed f16
    auto prep = [&](float vcur) -> float {
        if (lane < 32) LdsV[j] = vcur;
        __syncthreads();
        float m0 = fmaxf(LdsV[lane], LdsV[lane + 64]);
#pragma unroll
        for (int d = 1; d < 64; d <<= 1) m0 = fmaxf(m0, __shfl_xor(m0, d));
        float p  = __expf(vcur - m0);
        float pn = __shfl_xor(p, 1);
        if ((lane & 1) == 0 && lane < 32) {
            LdsP[j >> 1] = __builtin_bit_cast(unsigned int, pack_f16(p, pn));
        }
        __syncthreads();
        return m0;
    };

    // v for step t=2: prev0 + f_2 = f_1 + tr[start] + f_2
    float v2 = fbase[1 * L_DIM + j] + fbase[2 * L_DIM + j]
             + transfer[start * L_DIM + j];
    float m = prep(v2);

    float fa   = fbase[3 * L_DIM + j];   // f_{t+1} consumed at t=2
    float fbuf = fbase[4 * L_DIM + j];
    float newv = 0.f;

    for (int t = 2; t <= T_DIM - 1; ++t) {
        int tpre = t + 3; if (tpre > T_DIM - 1) tpre = T_DIM - 1;
        float fnew = fbase[tpre * L_DIM + j];   // distance-2 prefetch

        float acc = 0.f;
        const uint4* P4 = reinterpret_cast<const uint4*>(LdsP + (ihalf << 5));
#pragma unroll
        for (int c = 0; c < 8; ++c) {
            uint4 pv = P4[c];
            acc = fdot2_acc(__builtin_bit_cast(h2, pv.x), Ecol[4 * c + 0], acc);
            acc = fdot2_acc(__builtin_bit_cast(h2, pv.y), Ecol[4 * c + 1], acc);
            acc = fdot2_acc(__builtin_bit_cast(h2, pv.z), Ecol[4 * c + 2], acc);
            acc = fdot2_acc(__builtin_bit_cast(h2, pv.w), Ecol[4 * c + 3], acc);
        }
        acc += __shfl_xor(acc, 32);        // combine the two i-halves
        newv = m + __logf(acc);

        if (t < T_DIM - 1) {
            float vn = newv + fa;
            fa = fbuf; fbuf = fnew;
            m = prep(vn);
        }
    }

    // ---- sentence_score = LSE_j(prev_final + tr[j, stop]) ----
    float x  = newv + trStop;
    float mx = (lane < 32) ? x : -INFINITY;
#pragma unroll
    for (int d = 1; d < 64; d <<= 1) mx = fmaxf(mx, __shfl_xor(mx, d));
    float ex = (lane < 32) ? __expf(x - mx) : 0.f;
    float sm = ex;
#pragma unroll
    for (int d = 1; d < 64; d <<= 1) sm += __shfl_xor(sm, d);
    if (lane == 0) { LdsRed[wv] = mx; LdsRed[4 + wv] = sm; }

    // ---- gold score partial sums (all 256 threads) ----
    float es = 0.f, ts = 0.f;
    for (int t = 1 + tid; t < T_DIM; t += 256) {
        int tg = target[b * T_DIM + t];
        es += fbase[t * L_DIM + tg];
        int pr = (t == 1) ? start : target[b * T_DIM + t - 1];
        ts += transfer[pr * L_DIM + tg];
    }
#pragma unroll
    for (int d = 1; d < 64; d <<= 1) {
        es += __shfl_xor(es, d);
        ts += __shfl_xor(ts, d);
    }
    if (lane == 0) { LdsRed[8 + wv] = es; LdsRed[12 + wv] = ts; }
    __syncthreads();

    if (tid == 0) {
        float M = fmaxf(fmaxf(LdsRed[0], LdsRed[1]), fmaxf(LdsRed[2], LdsRed[3]));
        float S = 0.f;
        for (int k = 0; k < 4; ++k) S += LdsRed[4 + k] * __expf(LdsRed[k] - M);
        float sentence = M + __logf(S);
        float em = LdsRed[8] + LdsRed[9] + LdsRed[10] + LdsRed[11];
        float tn = LdsRed[12] + LdsRed[13] + LdsRed[14] + LdsRed[15];
        float emit0 = fbase[start];  // feats[b, 0, start]
        out[b] = sentence - __expf(emit0 + em + tn);
    }
}

extern "C" void kernel_launch(void* const* d_in, const int* in_sizes, int n_in,
                              void* d_out, int out_size, void* d_ws, size_t ws_size,
                              hipStream_t stream) {
    const float* feats    = (const float*)d_in[0];
    const float* transfer = (const float*)d_in[1];
    const int*   target   = (const int*)d_in[2];
    const int*   startp   = (const int*)d_in[3];
    const int*   stopp    = (const int*)d_in[4];
    float* outp = (float*)d_out;
    int B = in_sizes[0] / (T_DIM * L_DIM);
    hipLaunchKernelGGL(crf_fwd_kernel, dim3(B), dim3(256), 0, stream,
                       feats, transfer, target, startp, stopp, outp);
}

// Round 3
// 454.555 us; speedup vs baseline: 1.0897x; 1.0897x over previous
//
#include <hip/hip_runtime.h>
#include <hip/hip_bf16.h>

#define T_DIM 512
#define L_DIM 128

typedef _Float16 h2 __attribute__((ext_vector_type(2)));

#if defined(__has_builtin)
#if __has_builtin(__builtin_amdgcn_fdot2)
#define HAS_FDOT2 1
#endif
#endif

__device__ __forceinline__ float fdot2_acc(h2 a, h2 b, float c) {
#ifdef HAS_FDOT2
    return __builtin_amdgcn_fdot2(a, b, c, false);
#else
    return c + (float)a.x * (float)b.x + (float)a.y * (float)b.y;
#endif
}

__device__ __forceinline__ h2 pack_f16(float a, float b) {
    return __builtin_bit_cast(h2, __builtin_amdgcn_cvt_pkrtz(a, b));
}

// Block = 512 threads (8 waves) = one batch chain.
// Wave w owns j in [16w, 16w+16). Lane = (iq, jj): iq = lane>>4 picks
// i-quarter [32iq, 32iq+32); jj = lane&15 picks j = 16w + jj. Each lane
// keeps its E quarter-column (16 f16x2 pairs along i) in VGPRs.
//
// Scaling trick: p_i = exp(v_i - m_{w(i)}) with PER-WAVE reference
// m_w = v at the wave's first j (one broadcast shuffle, no max chain).
// Readers rescale each 16-i chunk by exp(m_c - m_0). Double-buffered
// LdsP/LdsM -> exactly ONE barrier per step.
__global__ __launch_bounds__(512, 4) void crf_fwd_kernel(
    const float* __restrict__ feats,
    const float* __restrict__ transfer,
    const int* __restrict__ target,
    const int* __restrict__ startp,
    const int* __restrict__ stopp,
    float* __restrict__ out)
{
    __shared__ unsigned int LdsP[2][64] __attribute__((aligned(16)));
    __shared__ float LdsM[2][8] __attribute__((aligned(16)));
    __shared__ float LdsRed[32];

    const int tid  = threadIdx.x;
    const int lane = tid & 63;
    const int wv   = tid >> 6;          // 0..7
    const int jj   = lane & 15;
    const int iq   = lane >> 4;         // 0..3
    const int j    = (wv << 4) | jj;    // 0..127
    const int i0   = iq << 5;           // 32*iq
    const int b    = blockIdx.x;
    const int start = startp[0];
    const int stop  = stopp[0];
    const float* fbase = feats + (size_t)b * T_DIM * L_DIM;

    // ---- one-time: E quarter-column into registers (f16 pairs along i) ----
    h2 Ecol[16];
#pragma unroll
    for (int q = 0; q < 16; ++q) {
        float e0 = __expf(transfer[(i0 + 2 * q)     * L_DIM + j]);
        float e1 = __expf(transfer[(i0 + 2 * q + 1) * L_DIM + j]);
        Ecol[q] = pack_f16(e0, e1);
    }
    const float trStop = transfer[j * L_DIM + stop];

    // ---- init: v for step t=2 is prev0 + f_2 = f_1 + tr[start] + f_2 ----
    {
        float v = fbase[1 * L_DIM + j] + fbase[2 * L_DIM + j]
                + transfer[start * L_DIM + j];
        float mw = __shfl(v, 0);                 // wave's reference
        float p  = __expf(v - mw);
        float pn = __shfl_xor(p, 1);
        if (lane == 0) LdsM[0][wv] = mw;
        if (iq == 0 && !(jj & 1))
            LdsP[0][j >> 1] = __builtin_bit_cast(unsigned int, pack_f16(p, pn));
    }
    float fa = fbase[3 * L_DIM + j];
    float fb = fbase[4 * L_DIM + j];
    __syncthreads();

    int cur = 0;
    float newv = 0.f;

    for (int t = 2; t <= T_DIM - 1; ++t) {
        int tp = t + 3; if (tp > T_DIM - 1) tp = T_DIM - 1;
        float fnew = fbase[tp * L_DIM + j];      // distance-2 prefetch

        const uint4* P4 = reinterpret_cast<const uint4*>(&LdsP[cur][0]);
        float2 mm  = *reinterpret_cast<const float2*>(&LdsM[cur][iq << 1]);
        float mref = LdsM[cur][0];

        uint4 pa = P4[(iq << 2) | 0];
        uint4 pb = P4[(iq << 2) | 1];
        uint4 pc = P4[(iq << 2) | 2];
        uint4 pd = P4[(iq << 2) | 3];

        float accA = 0.f, accB = 0.f;
        accA = fdot2_acc(__builtin_bit_cast(h2, pa.x), Ecol[0], accA);
        accA = fdot2_acc(__builtin_bit_cast(h2, pa.y), Ecol[1], accA);
        accA = fdot2_acc(__builtin_bit_cast(h2, pa.z), Ecol[2], accA);
        accA = fdot2_acc(__builtin_bit_cast(h2, pa.w), Ecol[3], accA);
        accA = fdot2_acc(__builtin_bit_cast(h2, pb.x), Ecol[4], accA);
        accA = fdot2_acc(__builtin_bit_cast(h2, pb.y), Ecol[5], accA);
        accA = fdot2_acc(__builtin_bit_cast(h2, pb.z), Ecol[6], accA);
        accA = fdot2_acc(__builtin_bit_cast(h2, pb.w), Ecol[7], accA);
        accB = fdot2_acc(__builtin_bit_cast(h2, pc.x), Ecol[8], accB);
        accB = fdot2_acc(__builtin_bit_cast(h2, pc.y), Ecol[9], accB);
        accB = fdot2_acc(__builtin_bit_cast(h2, pc.z), Ecol[10], accB);
        accB = fdot2_acc(__builtin_bit_cast(h2, pc.w), Ecol[11], accB);
        accB = fdot2_acc(__builtin_bit_cast(h2, pd.x), Ecol[12], accB);
        accB = fdot2_acc(__builtin_bit_cast(h2, pd.y), Ecol[13], accB);
        accB = fdot2_acc(__builtin_bit_cast(h2, pd.z), Ecol[14], accB);
        accB = fdot2_acc(__builtin_bit_cast(h2, pd.w), Ecol[15], accB);

        float s0 = __expf(mm.x - mref);
        float s1 = __expf(mm.y - mref);
        float acc = fmaf(s1, accB, s0 * accA);
        acc += __shfl_xor(acc, 16);              // combine i-quarters
        acc += __shfl_xor(acc, 32);
        newv = mref + __logf(acc);

        if (t < T_DIM - 1) {
            float vn = newv + fa;
            fa = fb; fb = fnew;
            float mw = __shfl(vn, 0);
            float p  = __expf(vn - mw);
            float pn = __shfl_xor(p, 1);
            if (lane == 0) LdsM[cur ^ 1][wv] = mw;
            if (iq == 0 && !(jj & 1))
                LdsP[cur ^ 1][j >> 1] =
                    __builtin_bit_cast(unsigned int, pack_f16(p, pn));
            __syncthreads();
            cur ^= 1;
        }
    }

    // ---- sentence_score = LSE_j(prev_final + tr[j, stop]) ----
    float x  = newv + trStop;
    float mx = x;
#pragma unroll
    for (int d = 1; d < 64; d <<= 1) mx = fmaxf(mx, __shfl_xor(mx, d));
    float ex = (iq == 0) ? __expf(x - mx) : 0.f;
#pragma unroll
    for (int d = 1; d < 64; d <<= 1) ex += __shfl_xor(ex, d);
    if (lane == 0) { LdsRed[wv] = mx; LdsRed[8 + wv] = ex; }

    // ---- gold score partial sums (one t per thread) ----
    float es = 0.f, ts = 0.f;
    {
        int t = 1 + tid;
        if (t < T_DIM) {
            int tg = target[b * T_DIM + t];
            es = fbase[t * L_DIM + tg];
            int pr = (t == 1) ? start : target[b * T_DIM + t - 1];
            ts = transfer[pr * L_DIM + tg];
        }
    }
#pragma unroll
    for (int d = 1; d < 64; d <<= 1) {
        es += __shfl_xor(es, d);
        ts += __shfl_xor(ts, d);
    }
    if (lane == 0) { LdsRed[16 + wv] = es; LdsRed[24 + wv] = ts; }
    __syncthreads();

    if (tid == 0) {
        float M = LdsRed[0];
#pragma unroll
        for (int k = 1; k < 8; ++k) M = fmaxf(M, LdsRed[k]);
        float S = 0.f;
#pragma unroll
        for (int k = 0; k < 8; ++k) S += LdsRed[8 + k] * __expf(LdsRed[k] - M);
        float sentence = M + __logf(S);
        float em = 0.f, tn = 0.f;
#pragma unroll
        for (int k = 0; k < 8; ++k) { em += LdsRed[16 + k]; tn += LdsRed[24 + k]; }
        float emit0 = fbase[start];              // feats[b, 0, start]
        out[b] = sentence - __expf(emit0 + em + tn);
    }
}

extern "C" void kernel_launch(void* const* d_in, const int* in_sizes, int n_in,
                              void* d_out, int out_size, void* d_ws, size_t ws_size,
                              hipStream_t stream) {
    const float* feats    = (const float*)d_in[0];
    const float* transfer = (const float*)d_in[1];
    const int*   target   = (const int*)d_in[2];
    const int*   startp   = (const int*)d_in[3];
    const int*   stopp    = (const int*)d_in[4];
    float* outp = (float*)d_out;
    int B = in_sizes[0] / (T_DIM * L_DIM);
    hipLaunchKernelGGL(crf_fwd_kernel, dim3(B), dim3(512), 0, stream,
                       feats, transfer, target, startp, stopp, outp);
}

// Round 4
// 396.250 us; speedup vs baseline: 1.2501x; 1.1471x over previous
//
#include <hip/hip_runtime.h>
#include <hip/hip_bf16.h>

#define T_DIM 512
#define L_DIM 128

typedef _Float16 h2 __attribute__((ext_vector_type(2)));

#if defined(__has_builtin)
#if __has_builtin(__builtin_amdgcn_fdot2)
#define HAS_FDOT2 1
#endif
#endif

__device__ __forceinline__ float fdot2_acc(h2 a, h2 b, float c) {
#ifdef HAS_FDOT2
    return __builtin_amdgcn_fdot2(a, b, c, false);
#else
    return c + (float)a.x * (float)b.x + (float)a.y * (float)b.y;
#endif
}

__device__ __forceinline__ h2 pack_f16(float a, float b) {
    return __builtin_bit_cast(h2, __builtin_amdgcn_cvt_pkrtz(a, b));
}

// LDS-only barrier: drains lgkmcnt but NOT vmcnt, so the global feats
// prefetch stays in flight across the step barrier (__syncthreads would
// emit s_waitcnt vmcnt(0) and put HBM latency on the critical path).
__device__ __forceinline__ void lds_barrier() {
    asm volatile("s_waitcnt lgkmcnt(0)\n\ts_barrier" ::: "memory");
}

// Block = 512 threads (8 waves) = one batch chain.
// Wave w owns j in [16w,16w+16). Lane = (iq,jj): iq=lane>>4 owns i-quarter
// [32iq,32iq+32); each lane keeps its E quarter-column (16 f16x2 pairs,
// pre-scaled by 1/128) in VGPRs.
//
// Multiplicative recurrence: u = exp(v - S) held in f16 (LdsU, double
// buffered, indexed by label). Per step: u'_j = (sum_i u_i*Ehat_ij)*exp(f_j).
// No per-step log/exp-of-state; scale tracked in S via u[0]-renorm every
// 16 steps. One log at the end.
__global__ __launch_bounds__(512, 4) void crf_fwd_kernel(
    const float* __restrict__ feats,
    const float* __restrict__ transfer,
    const int* __restrict__ target,
    const int* __restrict__ startp,
    const int* __restrict__ stopp,
    float* __restrict__ out)
{
    __shared__ unsigned short LdsU[2][L_DIM] __attribute__((aligned(16)));
    __shared__ float LdsRed[32];

    const int tid  = threadIdx.x;
    const int lane = tid & 63;
    const int wv   = tid >> 6;          // 0..7
    const int jj   = lane & 15;
    const int iq   = lane >> 4;         // 0..3
    const int j    = (wv << 4) | jj;    // 0..127
    const int i0   = iq << 5;           // 32*iq
    const int b    = blockIdx.x;
    const int start = startp[0];
    const int stop  = stopp[0];
    const float* fbase = feats + (size_t)b * T_DIM * L_DIM;
    const float LOG128 = 4.852030263919617f;

    // ---- one-time: Ehat = exp(transfer)/128, quarter-column in regs ----
    h2 Ecol[16];
#pragma unroll
    for (int q = 0; q < 16; ++q) {
        float e0 = __expf(transfer[(i0 + 2 * q)     * L_DIM + j]) * 0.0078125f;
        float e1 = __expf(transfer[(i0 + 2 * q + 1) * L_DIM + j]) * 0.0078125f;
        Ecol[q] = pack_f16(e0, e1);
    }
    const float trStop = transfer[j * L_DIM + stop];

    // ---- init: u = exp(f_1 + tr[start] + f_2)  (v2 is small, no norm) ----
    {
        float v2 = fbase[1 * L_DIM + j] + fbase[2 * L_DIM + j]
                 + transfer[start * L_DIM + j];
        if (iq == 0) {
            _Float16 h = (_Float16)__expf(v2);
            LdsU[0][j] = __builtin_bit_cast(unsigned short, h);
        }
    }
    float fa = fbase[3 * L_DIM + j];    // f_{t+1} consumed at t=2
    float fb = fbase[4 * L_DIM + j];
    float S  = 0.f;
    lds_barrier();

    int cur = 0;
    float accFinal = 0.f;

    for (int t = 2; t <= T_DIM - 1; ++t) {
        int tp = t + 3; if (tp > T_DIM - 1) tp = T_DIM - 1;
        float fnew = fbase[tp * L_DIM + j];   // in flight across barrier
        float fexp = __expf(fa);              // off the critical path

        if ((t & 15) == 0) {                  // periodic renorm, off-path
            _Float16 h0 = __builtin_bit_cast(_Float16, LdsU[cur][0]);
            float u0 = (float)h0;
            fexp *= 1.0f / u0;
            S += __logf(u0);
        }

        const uint4* P4 = reinterpret_cast<const uint4*>(&LdsU[cur][0]);
        uint4 pa = P4[(iq << 2) | 0];
        uint4 pb = P4[(iq << 2) | 1];
        uint4 pc = P4[(iq << 2) | 2];
        uint4 pd = P4[(iq << 2) | 3];

        float a0 = 0.f, a1 = 0.f, a2 = 0.f, a3 = 0.f;
        a0 = fdot2_acc(__builtin_bit_cast(h2, pa.x), Ecol[0],  a0);
        a0 = fdot2_acc(__builtin_bit_cast(h2, pa.y), Ecol[1],  a0);
        a0 = fdot2_acc(__builtin_bit_cast(h2, pa.z), Ecol[2],  a0);
        a0 = fdot2_acc(__builtin_bit_cast(h2, pa.w), Ecol[3],  a0);
        a1 = fdot2_acc(__builtin_bit_cast(h2, pb.x), Ecol[4],  a1);
        a1 = fdot2_acc(__builtin_bit_cast(h2, pb.y), Ecol[5],  a1);
        a1 = fdot2_acc(__builtin_bit_cast(h2, pb.z), Ecol[6],  a1);
        a1 = fdot2_acc(__builtin_bit_cast(h2, pb.w), Ecol[7],  a1);
        a2 = fdot2_acc(__builtin_bit_cast(h2, pc.x), Ecol[8],  a2);
        a2 = fdot2_acc(__builtin_bit_cast(h2, pc.y), Ecol[9],  a2);
        a2 = fdot2_acc(__builtin_bit_cast(h2, pc.z), Ecol[10], a2);
        a2 = fdot2_acc(__builtin_bit_cast(h2, pc.w), Ecol[11], a2);
        a3 = fdot2_acc(__builtin_bit_cast(h2, pd.x), Ecol[12], a3);
        a3 = fdot2_acc(__builtin_bit_cast(h2, pd.y), Ecol[13], a3);
        a3 = fdot2_acc(__builtin_bit_cast(h2, pd.z), Ecol[14], a3);
        a3 = fdot2_acc(__builtin_bit_cast(h2, pd.w), Ecol[15], a3);
        float acc = (a0 + a1) + (a2 + a3);

        acc += __shfl_xor(acc, 16);           // combine i-quarters
        acc += __shfl_xor(acc, 32);

        if (t < T_DIM - 1) {
            float un = acc * fexp;
            fa = fb; fb = fnew;
            if (iq == 0) {
                _Float16 h = (_Float16)un;
                LdsU[cur ^ 1][j] = __builtin_bit_cast(unsigned short, h);
            }
            lds_barrier();
            cur ^= 1;
        } else {
            accFinal = acc;
        }
    }

    // 510 dots, each carrying the folded 1/128
    S += 510.0f * LOG128;

    // ---- sentence_score = LSE_j(log(u_j) + S + tr[j, stop]) ----
    float x  = __logf(accFinal) + S + trStop;
    float mx = x;
#pragma unroll
    for (int d = 1; d < 64; d <<= 1) mx = fmaxf(mx, __shfl_xor(mx, d));
    float ex = (iq == 0) ? __expf(x - mx) : 0.f;
#pragma unroll
    for (int d = 1; d < 64; d <<= 1) ex += __shfl_xor(ex, d);
    if (lane == 0) { LdsRed[wv] = mx; LdsRed[8 + wv] = ex; }

    // ---- gold score partial sums (one t per thread) ----
    float es = 0.f, ts = 0.f;
    {
        int t = 1 + tid;
        if (t < T_DIM) {
            int tg = target[b * T_DIM + t];
            es = fbase[t * L_DIM + tg];
            int pr = (t == 1) ? start : target[b * T_DIM + t - 1];
            ts = transfer[pr * L_DIM + tg];
        }
    }
#pragma unroll
    for (int d = 1; d < 64; d <<= 1) {
        es += __shfl_xor(es, d);
        ts += __shfl_xor(ts, d);
    }
    if (lane == 0) { LdsRed[16 + wv] = es; LdsRed[24 + wv] = ts; }
    __syncthreads();

    if (tid == 0) {
        float M = LdsRed[0];
#pragma unroll
        for (int k = 1; k < 8; ++k) M = fmaxf(M, LdsRed[k]);
        float Ssum = 0.f;
#pragma unroll
        for (int k = 0; k < 8; ++k) Ssum += LdsRed[8 + k] * __expf(LdsRed[k] - M);
        float sentence = M + __logf(Ssum);
        float em = 0.f, tn = 0.f;
#pragma unroll
        for (int k = 0; k < 8; ++k) { em += LdsRed[16 + k]; tn += LdsRed[24 + k]; }
        float emit0 = fbase[start];           // feats[b, 0, start]
        out[b] = sentence - __expf(emit0 + em + tn);
    }
}

extern "C" void kernel_launch(void* const* d_in, const int* in_sizes, int n_in,
                              void* d_out, int out_size, void* d_ws, size_t ws_size,
                              hipStream_t stream) {
    const float* feats    = (const float*)d_in[0];
    const float* transfer = (const float*)d_in[1];
    const int*   target   = (const int*)d_in[2];
    const int*   startp   = (const int*)d_in[3];
    const int*   stopp    = (const int*)d_in[4];
    float* outp = (float*)d_out;
    int B = in_sizes[0] / (T_DIM * L_DIM);
    hipLaunchKernelGGL(crf_fwd_kernel, dim3(B), dim3(512), 0, stream,
                       feats, transfer, target, startp, stopp, outp);
}